// Round 1
// baseline (23671.625 us; speedup 1.0000x reference)
//
#include <hip/hip_runtime.h>

typedef _Float16 f16;
typedef _Float16 half8 __attribute__((ext_vector_type(8)));
typedef float f32x4 __attribute__((ext_vector_type(4)));

#define HIDDEN 1024
#define NSER 512
#define BATCH 256
#define TSTEPS 512

__device__ __forceinline__ float tanh_fast(float x) {
  x = fminf(15.0f, fmaxf(-15.0f, x));
  float e = __expf(2.0f * x);
  return (e - 1.0f) / (e + 1.0f);
}

// ---------------- prep kernels ----------------

// WhLh[j][k] = f16(Wh[j][k])  (left half of Wh)
__global__ __launch_bounds__(256) void convert_whl_kernel(const float* __restrict__ Wh,
                                                          f16* __restrict__ WhLh) {
  int idx = blockIdx.x * 256 + threadIdx.x;  // 1024*1024
  int j = idx >> 10, k = idx & 1023;
  WhLh[idx] = (f16)Wh[((size_t)j << 11) + k];
}

__global__ __launch_bounds__(256) void convert_wl_kernel(const float* __restrict__ Wl,
                                                         f16* __restrict__ Wlh) {
  int idx = blockIdx.x * 256 + threadIdx.x;  // 512*1024
  Wlh[idx] = (f16)Wl[idx];
}

// WiT[n][k] = f16(Wi[k][n]);  Wi is [1024][512]
__global__ __launch_bounds__(256) void transpose_wi_kernel(const float* __restrict__ Wi,
                                                           f16* __restrict__ WiT) {
  __shared__ float tile[32][33];
  int tx = threadIdx.x & 31, ty = threadIdx.x >> 5;
  int c0 = blockIdx.x * 32;  // n (512)
  int r0 = blockIdx.y * 32;  // k (1024)
#pragma unroll
  for (int i = 0; i < 32; i += 8)
    tile[ty + i][tx] = Wi[(size_t)(r0 + ty + i) * NSER + c0 + tx];
  __syncthreads();
#pragma unroll
  for (int i = 0; i < 32; i += 8)
    WiT[(size_t)(c0 + ty + i) * HIDDEN + r0 + tx] = (f16)tile[tx][ty + i];
}

// xT[t][b][n] = f16(x[b][n][t])
__global__ __launch_bounds__(256) void transpose_x_kernel(const float* __restrict__ x,
                                                          f16* __restrict__ xT) {
  __shared__ float tile[32][33];
  int b = blockIdx.z;
  int t0 = blockIdx.x * 32, n0 = blockIdx.y * 32;
  int tx = threadIdx.x & 31, ty = threadIdx.x >> 5;
#pragma unroll
  for (int i = 0; i < 32; i += 8)
    tile[ty + i][tx] = x[((size_t)b * NSER + n0 + ty + i) * TSTEPS + t0 + tx];
  __syncthreads();
#pragma unroll
  for (int i = 0; i < 32; i += 8)
    xT[((size_t)(t0 + ty + i) * BATCH + b) * NSER + n0 + tx] = (f16)tile[tx][ty + i];
}

// beff[j] = bh[j] + sum_k Wh[j][k]*bi[k]  (k < 1024)
__global__ __launch_bounds__(256) void beff_kernel(const float* __restrict__ Wh,
                                                   const float* __restrict__ bi,
                                                   const float* __restrict__ bh,
                                                   float* __restrict__ beff) {
  __shared__ float red[256];
  int j = blockIdx.x;
  float s = 0.f;
  for (int k = threadIdx.x; k < HIDDEN; k += 256)
    s += Wh[(size_t)j * 2048 + k] * bi[k];
  red[threadIdx.x] = s;
  __syncthreads();
  for (int off = 128; off > 0; off >>= 1) {
    if (threadIdx.x < (unsigned)off) red[threadIdx.x] += red[threadIdx.x + off];
    __syncthreads();
  }
  if (threadIdx.x == 0) beff[j] = bh[j] + red[0];
}

// ---------------- generic f16 MFMA GEMM: C[M,N] = A[M,K] * B[N,K]^T (+bias[n]) ----------------
// BM=BN=128, BK=64, 256 threads (4 waves, 2x2 of 64x64), reg-staged LDS.
template <bool OUT_F16, bool HAS_BIAS>
__global__ __launch_bounds__(256) void gemm_f16_kernel(const f16* __restrict__ A,
                                                       const f16* __restrict__ B,
                                                       const float* __restrict__ bias,
                                                       void* __restrict__ Cp,
                                                       int M, int N, int K) {
  (void)M;
  __shared__ f16 As[128 * 64];
  __shared__ f16 Bs[128 * 64];
  const int tid = threadIdx.x;
  const int l = tid & 63, w = tid >> 6;
  const int wr = w >> 1, wc = w & 1;
  const int lr = l & 15, lg = l >> 4;
  const size_t m0 = (size_t)blockIdx.y * 128, n0 = (size_t)blockIdx.x * 128;
  f32x4 acc[4][4] = {};
  for (int k0 = 0; k0 < K; k0 += 64) {
    half8 ar[4], br[4];
#pragma unroll
    for (int c = 0; c < 4; ++c) {
      int Gq = c * 256 + tid;            // granule 0..1023 (16B each)
      int row = Gq >> 3, colg = Gq & 7;  // row 0..127, col granule 0..7
      ar[c] = *(const half8*)&A[(m0 + row) * K + k0 + colg * 8];
      br[c] = *(const half8*)&B[(n0 + row) * K + k0 + colg * 8];
    }
    __syncthreads();  // previous iter's LDS reads done
#pragma unroll
    for (int c = 0; c < 4; ++c) {
      int Gq = c * 256 + tid;
      *(half8*)&As[Gq * 8] = ar[c];
      *(half8*)&Bs[Gq * 8] = br[c];
    }
    __syncthreads();
#pragma unroll
    for (int ks = 0; ks < 2; ++ks) {
      half8 a[4], b[4];
#pragma unroll
      for (int i = 0; i < 4; ++i)
        a[i] = *(const half8*)&As[(wr * 64 + i * 16 + lr) * 64 + ks * 32 + lg * 8];
#pragma unroll
      for (int i = 0; i < 4; ++i)
        b[i] = *(const half8*)&Bs[(wc * 64 + i * 16 + lr) * 64 + ks * 32 + lg * 8];
#pragma unroll
      for (int mi = 0; mi < 4; ++mi)
#pragma unroll
        for (int ni = 0; ni < 4; ++ni)
          acc[mi][ni] = __builtin_amdgcn_mfma_f32_16x16x32_f16(a[mi], b[ni], acc[mi][ni], 0, 0, 0);
    }
  }
#pragma unroll
  for (int mi = 0; mi < 4; ++mi) {
#pragma unroll
    for (int ni = 0; ni < 4; ++ni) {
      size_t n = n0 + wc * 64 + ni * 16 + lr;
      float bv = 0.f;
      if constexpr (HAS_BIAS) bv = bias[n];
#pragma unroll
      for (int r = 0; r < 4; ++r) {
        size_t m = m0 + wr * 64 + mi * 16 + lg * 4 + r;
        float v = acc[mi][ni][r] + bv;
        if constexpr (OUT_F16)
          ((f16*)Cp)[m * (size_t)N + n] = (f16)v;
        else
          ((float*)Cp)[m * (size_t)N + n] = v;
      }
    }
  }
}

// ---------------- persistent recurrent kernel ----------------
// 256 blocks = 16 b-groups (16 batch rows each) x 16 j-groups (64 cols each).
// WhR j-slice lives in registers (32 x half8 per lane). Per step: stage this
// b-group's h[16][1024] (f16) into swizzled LDS, 32 MFMAs, tanh, publish,
// per-group barrier (per-step counters, per-wave release adds).
__global__ __launch_bounds__(256) void rnn_kernel(const float* __restrict__ Wh,
                                                  const f16* __restrict__ Z,
                                                  f16* hb0, f16* hb1,
                                                  float* __restrict__ h_final,
                                                  unsigned int* cnt) {
  const int bid = blockIdx.x;
  const int g = bid >> 4, q = bid & 15;
  const int tid = threadIdx.x;
  const int l = tid & 63, w = tid >> 6;
  const int lr = l & 15, lg = l >> 4;
  const int b0 = g * 16;
  const int jcol = q * 64 + w * 16 + lr;

  // B-fragments of WhR row jcol, converted f32->f16 once.
  half8 breg[32];
#pragma unroll
  for (int ks = 0; ks < 32; ++ks) {
    const float* s = &Wh[(size_t)jcol * 2048 + HIDDEN + ks * 32 + lg * 8];
    half8 hv;
#pragma unroll
    for (int i = 0; i < 8; ++i) hv[i] = (f16)s[i];
    breg[ks] = hv;
  }

  __shared__ f16 hs[16 * HIDDEN];  // 32KB, 16B-granule XOR swizzle

  for (int t = 0; t < TSTEPS; ++t) {
    const f16* hprev = (t & 1) ? hb1 : hb0;
    f16* hnext = (t & 1) ? hb0 : hb1;

    // prefetch Z for this lane's 4 output rows (independent of h)
    const f16* zp = &Z[((size_t)t * BATCH + b0 + lg * 4) * HIDDEN + jcol];
    f16 z0 = zp[0], z1 = zp[HIDDEN], z2 = zp[2 * HIDDEN], z3 = zp[3 * HIDDEN];

    // stage h[b0..b0+15][0..1023] into LDS (swizzled granules)
#pragma unroll
    for (int i = 0; i < 8; ++i) {
      int G = i * 256 + tid;          // 2048 granules of 8 f16
      int row = G >> 7, gI = G & 127;
      half8 v = *(const half8*)&hprev[(size_t)(b0 + row) * HIDDEN + gI * 8];
      *(half8*)&hs[row * HIDDEN + ((gI ^ (row & 7)) * 8)] = v;
    }
    __syncthreads();

    f32x4 acc = {0.f, 0.f, 0.f, 0.f};
#pragma unroll
    for (int ks = 0; ks < 32; ++ks) {
      int gA = ks * 4 + lg;
      half8 a = *(const half8*)&hs[lr * HIDDEN + ((gA ^ (lr & 7)) * 8)];
      acc = __builtin_amdgcn_mfma_f32_16x16x32_f16(a, breg[ks], acc, 0, 0, 0);
    }

    float v0 = tanh_fast(acc[0] + (float)z0);
    float v1 = tanh_fast(acc[1] + (float)z1);
    float v2 = tanh_fast(acc[2] + (float)z2);
    float v3 = tanh_fast(acc[3] + (float)z3);

    if (t == TSTEPS - 1) {
      h_final[(size_t)(b0 + lg * 4 + 0) * HIDDEN + jcol] = v0;
      h_final[(size_t)(b0 + lg * 4 + 1) * HIDDEN + jcol] = v1;
      h_final[(size_t)(b0 + lg * 4 + 2) * HIDDEN + jcol] = v2;
      h_final[(size_t)(b0 + lg * 4 + 3) * HIDDEN + jcol] = v3;
    } else {
      hnext[(size_t)(b0 + lg * 4 + 0) * HIDDEN + jcol] = (f16)v0;
      hnext[(size_t)(b0 + lg * 4 + 1) * HIDDEN + jcol] = (f16)v1;
      hnext[(size_t)(b0 + lg * 4 + 2) * HIDDEN + jcol] = (f16)v2;
      hnext[(size_t)(b0 + lg * 4 + 3) * HIDDEN + jcol] = (f16)v3;

      // per-group barrier: 16 blocks x 4 waves = 64 arrivals on a per-step counter.
      // release RMW drains this wave's stores (vmcnt) and publishes agent-wide.
      if (l == 0)
        __hip_atomic_fetch_add(&cnt[g * TSTEPS + t], 1u, __ATOMIC_RELEASE,
                               __HIP_MEMORY_SCOPE_AGENT);
      int guard = 0;
      while (__hip_atomic_load(&cnt[g * TSTEPS + t], __ATOMIC_RELAXED,
                               __HIP_MEMORY_SCOPE_AGENT) < 64u) {
        __builtin_amdgcn_s_sleep(1);
        if (++guard > (1 << 18)) break;  // fail-safe: wrong answer instead of hang
      }
      __threadfence();  // acquire: subsequent h reads see remote writes
    }
    // LDS reuse safe: count==64 implies every wave finished its K-loop reads.
  }
}

// ---------------- BatchNorm (training stats, biased var) + f16 cast ----------------
__global__ __launch_bounds__(256) void bn_kernel(const float* __restrict__ hf,
                                                 const float* __restrict__ gamma,
                                                 const float* __restrict__ beta,
                                                 f16* __restrict__ hbn) {
  int j = blockIdx.x * 256 + threadIdx.x;  // 1024 cols
  float s1 = 0.f, s2 = 0.f;
  for (int b = 0; b < BATCH; ++b) {
    float v = hf[(size_t)b * HIDDEN + j];
    s1 += v;
    s2 += v * v;
  }
  float mean = s1 * (1.f / BATCH);
  float var = s2 * (1.f / BATCH) - mean * mean;
  float sc = gamma[j] * rsqrtf(var + 1e-5f);
  float sh = beta[j] - mean * sc;
  for (int b = 0; b < BATCH; ++b)
    hbn[(size_t)b * HIDDEN + j] = (f16)(hf[(size_t)b * HIDDEN + j] * sc + sh);
}

// ---------------- launch ----------------
extern "C" void kernel_launch(void* const* d_in, const int* in_sizes, int n_in,
                              void* d_out, int out_size, void* d_ws, size_t ws_size,
                              hipStream_t stream) {
  (void)in_sizes; (void)n_in; (void)out_size;
  const float* x     = (const float*)d_in[0];
  const float* Wi    = (const float*)d_in[1];
  const float* bi    = (const float*)d_in[2];
  const float* Wh    = (const float*)d_in[3];
  const float* bh    = (const float*)d_in[4];
  const float* gamma = (const float*)d_in[5];
  const float* beta  = (const float*)d_in[6];
  const float* Wl    = (const float*)d_in[7];
  const float* bl    = (const float*)d_in[8];
  float* out = (float*)d_out;

  char* wsp = (char*)d_ws;
  size_t off = 0;
  auto alloc = [&](size_t bytes) -> void* {
    void* p = (void*)(wsp + off);
    off += (bytes + 255) & ~(size_t)255;
    return p;
  };
  f16*      Zb    = (f16*)alloc((size_t)TSTEPS * BATCH * HIDDEN * 2);  // 256 MB
  f16*      xT    = (f16*)alloc((size_t)TSTEPS * BATCH * NSER * 2);    // 128 MB
  f16*      WhLh  = (f16*)alloc((size_t)HIDDEN * HIDDEN * 2);
  f16*      WiT   = (f16*)alloc((size_t)NSER * HIDDEN * 2);
  f16*      Wlh   = (f16*)alloc((size_t)NSER * HIDDEN * 2);
  f16*      Weff  = (f16*)alloc((size_t)HIDDEN * NSER * 2);
  float*    beff  = (float*)alloc(HIDDEN * 4);
  f16*      hbuf0 = (f16*)alloc((size_t)BATCH * HIDDEN * 2);
  f16*      hbuf1 = (f16*)alloc((size_t)BATCH * HIDDEN * 2);
  float*    hfin  = (float*)alloc((size_t)BATCH * HIDDEN * 4);
  f16*      hbn   = (f16*)alloc((size_t)BATCH * HIDDEN * 2);
  unsigned* cnt   = (unsigned*)alloc(16 * TSTEPS * 4);
  if (off > ws_size) return;  // workspace too small; fail visibly

  hipMemsetAsync(cnt, 0, 16 * TSTEPS * 4, stream);
  hipMemsetAsync(hbuf0, 0, (size_t)BATCH * HIDDEN * 2, stream);  // h_0 = 0

  convert_whl_kernel<<<4096, 256, 0, stream>>>(Wh, WhLh);
  transpose_wi_kernel<<<dim3(16, 32), 256, 0, stream>>>(Wi, WiT);
  convert_wl_kernel<<<2048, 256, 0, stream>>>(Wl, Wlh);
  beff_kernel<<<1024, 256, 0, stream>>>(Wh, bi, bh, beff);
  // Weff[j][n] = sum_k WhL[j][k] * WiT[n][k] : M=1024, N=512, K=1024
  gemm_f16_kernel<true, false><<<dim3(4, 8), 256, 0, stream>>>(WhLh, WiT, nullptr, Weff,
                                                               1024, NSER, HIDDEN);
  transpose_x_kernel<<<dim3(16, 16, 256), 256, 0, stream>>>(x, xT);
  // Z[(t,b)][j] = sum_n xT[(t,b)][n] * Weff[j][n] + beff[j] : M=131072, N=1024, K=512
  gemm_f16_kernel<true, true><<<dim3(8, 1024), 256, 0, stream>>>(xT, Weff, beff, Zb,
                                                                 TSTEPS * BATCH, HIDDEN, NSER);
  rnn_kernel<<<256, 256, 0, stream>>>(Wh, Zb, hbuf0, hbuf1, hfin, cnt);
  bn_kernel<<<4, 256, 0, stream>>>(hfin, gamma, beta, hbn);
  // out[b][i] = sum_j hbn[b][j] * Wl[i][j] + bl[i] : M=256, N=512, K=1024
  gemm_f16_kernel<false, true><<<dim3(4, 2), 256, 0, stream>>>(hbn, Wlh, bl, out,
                                                               BATCH, NSER, HIDDEN);
}

// Round 2
// 2504.409 us; speedup vs baseline: 9.4520x; 9.4520x over previous
//
#include <hip/hip_runtime.h>

typedef _Float16 f16;
typedef _Float16 half8 __attribute__((ext_vector_type(8)));
typedef float f32x4 __attribute__((ext_vector_type(4)));

#define HIDDEN 1024
#define NSER 512
#define BATCH 256
#define TSTEPS 512

__device__ __forceinline__ float tanh_fast(float x) {
  x = fminf(15.0f, fmaxf(-15.0f, x));
  float e = __expf(2.0f * x);
  return (e - 1.0f) / (e + 1.0f);
}

// ---------------- prep kernels ----------------

// WhLh[j][k] = f16(Wh[j][k])  (left half of Wh)
__global__ __launch_bounds__(256) void convert_whl_kernel(const float* __restrict__ Wh,
                                                          f16* __restrict__ WhLh) {
  int idx = blockIdx.x * 256 + threadIdx.x;  // 1024*1024
  int j = idx >> 10, k = idx & 1023;
  WhLh[idx] = (f16)Wh[((size_t)j << 11) + k];
}

__global__ __launch_bounds__(256) void convert_wl_kernel(const float* __restrict__ Wl,
                                                         f16* __restrict__ Wlh) {
  int idx = blockIdx.x * 256 + threadIdx.x;  // 512*1024
  Wlh[idx] = (f16)Wl[idx];
}

// WiT[n][k] = f16(Wi[k][n]);  Wi is [1024][512]
__global__ __launch_bounds__(256) void transpose_wi_kernel(const float* __restrict__ Wi,
                                                           f16* __restrict__ WiT) {
  __shared__ float tile[32][33];
  int tx = threadIdx.x & 31, ty = threadIdx.x >> 5;
  int c0 = blockIdx.x * 32;  // n (512)
  int r0 = blockIdx.y * 32;  // k (1024)
#pragma unroll
  for (int i = 0; i < 32; i += 8)
    tile[ty + i][tx] = Wi[(size_t)(r0 + ty + i) * NSER + c0 + tx];
  __syncthreads();
#pragma unroll
  for (int i = 0; i < 32; i += 8)
    WiT[(size_t)(c0 + ty + i) * HIDDEN + r0 + tx] = (f16)tile[tx][ty + i];
}

// xT[t][b][n] = f16(x[b][n][t])
__global__ __launch_bounds__(256) void transpose_x_kernel(const float* __restrict__ x,
                                                          f16* __restrict__ xT) {
  __shared__ float tile[32][33];
  int b = blockIdx.z;
  int t0 = blockIdx.x * 32, n0 = blockIdx.y * 32;
  int tx = threadIdx.x & 31, ty = threadIdx.x >> 5;
#pragma unroll
  for (int i = 0; i < 32; i += 8)
    tile[ty + i][tx] = x[((size_t)b * NSER + n0 + ty + i) * TSTEPS + t0 + tx];
  __syncthreads();
#pragma unroll
  for (int i = 0; i < 32; i += 8)
    xT[((size_t)(t0 + ty + i) * BATCH + b) * NSER + n0 + tx] = (f16)tile[tx][ty + i];
}

// beff[j] = bh[j] + sum_k Wh[j][k]*bi[k]  (k < 1024)
__global__ __launch_bounds__(256) void beff_kernel(const float* __restrict__ Wh,
                                                   const float* __restrict__ bi,
                                                   const float* __restrict__ bh,
                                                   float* __restrict__ beff) {
  __shared__ float red[256];
  int j = blockIdx.x;
  float s = 0.f;
  for (int k = threadIdx.x; k < HIDDEN; k += 256)
    s += Wh[(size_t)j * 2048 + k] * bi[k];
  red[threadIdx.x] = s;
  __syncthreads();
  for (int off = 128; off > 0; off >>= 1) {
    if (threadIdx.x < (unsigned)off) red[threadIdx.x] += red[threadIdx.x + off];
    __syncthreads();
  }
  if (threadIdx.x == 0) beff[j] = bh[j] + red[0];
}

// ---------------- generic f16 MFMA GEMM: C[M,N] = A[M,K] * B[N,K]^T (+bias[n]) ----------------
template <bool OUT_F16, bool HAS_BIAS>
__global__ __launch_bounds__(256) void gemm_f16_kernel(const f16* __restrict__ A,
                                                       const f16* __restrict__ B,
                                                       const float* __restrict__ bias,
                                                       void* __restrict__ Cp,
                                                       int M, int N, int K) {
  (void)M;
  __shared__ f16 As[128 * 64];
  __shared__ f16 Bs[128 * 64];
  const int tid = threadIdx.x;
  const int l = tid & 63, w = tid >> 6;
  const int wr = w >> 1, wc = w & 1;
  const int lr = l & 15, lg = l >> 4;
  const size_t m0 = (size_t)blockIdx.y * 128, n0 = (size_t)blockIdx.x * 128;
  f32x4 acc[4][4] = {};
  for (int k0 = 0; k0 < K; k0 += 64) {
    half8 ar[4], br[4];
#pragma unroll
    for (int c = 0; c < 4; ++c) {
      int Gq = c * 256 + tid;            // granule 0..1023 (16B each)
      int row = Gq >> 3, colg = Gq & 7;  // row 0..127, col granule 0..7
      ar[c] = *(const half8*)&A[(m0 + row) * K + k0 + colg * 8];
      br[c] = *(const half8*)&B[(n0 + row) * K + k0 + colg * 8];
    }
    __syncthreads();  // previous iter's LDS reads done
#pragma unroll
    for (int c = 0; c < 4; ++c) {
      int Gq = c * 256 + tid;
      *(half8*)&As[Gq * 8] = ar[c];
      *(half8*)&Bs[Gq * 8] = br[c];
    }
    __syncthreads();
#pragma unroll
    for (int ks = 0; ks < 2; ++ks) {
      half8 a[4], b[4];
#pragma unroll
      for (int i = 0; i < 4; ++i)
        a[i] = *(const half8*)&As[(wr * 64 + i * 16 + lr) * 64 + ks * 32 + lg * 8];
#pragma unroll
      for (int i = 0; i < 4; ++i)
        b[i] = *(const half8*)&Bs[(wc * 64 + i * 16 + lr) * 64 + ks * 32 + lg * 8];
#pragma unroll
      for (int mi = 0; mi < 4; ++mi)
#pragma unroll
        for (int ni = 0; ni < 4; ++ni)
          acc[mi][ni] = __builtin_amdgcn_mfma_f32_16x16x32_f16(a[mi], b[ni], acc[mi][ni], 0, 0, 0);
    }
  }
#pragma unroll
  for (int mi = 0; mi < 4; ++mi) {
#pragma unroll
    for (int ni = 0; ni < 4; ++ni) {
      size_t n = n0 + wc * 64 + ni * 16 + lr;
      float bv = 0.f;
      if constexpr (HAS_BIAS) bv = bias[n];
#pragma unroll
      for (int r = 0; r < 4; ++r) {
        size_t m = m0 + wr * 64 + mi * 16 + lg * 4 + r;
        float v = acc[mi][ni][r] + bv;
        if constexpr (OUT_F16)
          ((f16*)Cp)[m * (size_t)N + n] = (f16)v;
        else
          ((float*)Cp)[m * (size_t)N + n] = v;
      }
    }
  }
}

// ---------------- persistent recurrent kernel ----------------
// 256 blocks = 16 b-groups x 16 j-groups. WhR j-slice in registers. Per step:
// device-coherent (sc0 sc1, MALL-serviced) h exchange + relaxed-atomic barrier.
// NO acquire/release fences -> no buffer_inv/wbl2 per step (that was 99% of R1).
__global__ __launch_bounds__(256) void rnn_kernel(const float* __restrict__ Wh,
                                                  const f16* __restrict__ Z,
                                                  f16* hb0, f16* hb1,
                                                  float* __restrict__ h_final,
                                                  unsigned int* cnt) {
  const int bid = blockIdx.x;
  const int g = bid >> 4, q = bid & 15;
  const int tid = threadIdx.x;
  const int l = tid & 63, w = tid >> 6;
  const int lr = l & 15, lg = l >> 4;
  const int b0 = g * 16;
  const int jcol = q * 64 + w * 16 + lr;

  // B-fragments of WhR row jcol, converted f32->f16 once.
  half8 breg[32];
#pragma unroll
  for (int ks = 0; ks < 32; ++ks) {
    const float* s = &Wh[(size_t)jcol * 2048 + HIDDEN + ks * 32 + lg * 8];
    half8 hv;
#pragma unroll
    for (int i = 0; i < 8; ++i) hv[i] = (f16)s[i];
    breg[ks] = hv;
  }

  __shared__ f16 hs[16 * HIDDEN];  // 32KB, 16B-granule XOR swizzle

  for (int t = 0; t < TSTEPS; ++t) {
    const f16* hprev = (t & 1) ? hb1 : hb0;
    f16* hnext = (t & 1) ? hb0 : hb1;

    // Z prefetch (read-only, regular cached loads)
    const f16* zp = &Z[((size_t)t * BATCH + b0 + lg * 4) * HIDDEN + jcol];
    f16 z0 = zp[0], z1 = zp[HIDDEN], z2 = zp[2 * HIDDEN], z3 = zp[3 * HIDDEN];

    // load h[b0..b0+15][0..1023] into regs: 8 x 16B granules per thread.
    half8 hv[8];
    if (t == 0) {
#pragma unroll
      for (int i = 0; i < 8; ++i) {
        int G = i * 256 + tid;
        int row = G >> 7, gI = G & 127;
        hv[i] = *(const half8*)&hprev[(size_t)(b0 + row) * HIDDEN + gI * 8];
      }
    } else {
      // device-coherent loads: bypass (possibly stale) L1/L2, hit the MALL.
#pragma unroll
      for (int i = 0; i < 8; ++i) {
        int G = i * 256 + tid;
        int row = G >> 7, gI = G & 127;
        const f16* src = &hprev[(size_t)(b0 + row) * HIDDEN + gI * 8];
        asm volatile("global_load_dwordx4 %0, %1, off sc0 sc1"
                     : "=v"(hv[i])
                     : "v"(src));
      }
    }
    asm volatile("s_waitcnt vmcnt(0)" ::: "memory");  // loads landed in hv[]

    // stage into swizzled LDS
#pragma unroll
    for (int i = 0; i < 8; ++i) {
      int G = i * 256 + tid;
      int row = G >> 7, gI = G & 127;
      *(half8*)&hs[row * HIDDEN + ((gI ^ (row & 7)) * 8)] = hv[i];
    }
    __syncthreads();

    f32x4 acc = {0.f, 0.f, 0.f, 0.f};
#pragma unroll
    for (int ks = 0; ks < 32; ++ks) {
      int gA = ks * 4 + lg;
      half8 a = *(const half8*)&hs[lr * HIDDEN + ((gA ^ (lr & 7)) * 8)];
      acc = __builtin_amdgcn_mfma_f32_16x16x32_f16(a, breg[ks], acc, 0, 0, 0);
    }

    float v0 = tanh_fast(acc[0] + (float)z0);
    float v1 = tanh_fast(acc[1] + (float)z1);
    float v2 = tanh_fast(acc[2] + (float)z2);
    float v3 = tanh_fast(acc[3] + (float)z3);

    if (t == TSTEPS - 1) {
      h_final[(size_t)(b0 + lg * 4 + 0) * HIDDEN + jcol] = v0;
      h_final[(size_t)(b0 + lg * 4 + 1) * HIDDEN + jcol] = v1;
      h_final[(size_t)(b0 + lg * 4 + 2) * HIDDEN + jcol] = v2;
      h_final[(size_t)(b0 + lg * 4 + 3) * HIDDEN + jcol] = v3;
    } else {
      // device-coherent write-through 2B stores (no L2-dirty state to flush)
      unsigned s0 = (unsigned)__builtin_bit_cast(unsigned short, (f16)v0);
      unsigned s1 = (unsigned)__builtin_bit_cast(unsigned short, (f16)v1);
      unsigned s2 = (unsigned)__builtin_bit_cast(unsigned short, (f16)v2);
      unsigned s3 = (unsigned)__builtin_bit_cast(unsigned short, (f16)v3);
      f16* p0 = &hnext[(size_t)(b0 + lg * 4 + 0) * HIDDEN + jcol];
      asm volatile("global_store_short %0, %1, off sc0 sc1" ::"v"(p0), "v"(s0) : "memory");
      asm volatile("global_store_short %0, %1, off sc0 sc1" ::"v"(p0 + HIDDEN), "v"(s1) : "memory");
      asm volatile("global_store_short %0, %1, off sc0 sc1" ::"v"(p0 + 2 * HIDDEN), "v"(s2) : "memory");
      asm volatile("global_store_short %0, %1, off sc0 sc1" ::"v"(p0 + 3 * HIDDEN), "v"(s3) : "memory");
      asm volatile("s_waitcnt vmcnt(0)" ::: "memory");  // stores globally visible
      __syncthreads();                                   // whole block done
      if (tid == 0)
        __hip_atomic_fetch_add(&cnt[g * TSTEPS + t], 1u, __ATOMIC_RELAXED,
                               __HIP_MEMORY_SCOPE_AGENT);
      int guard = 0;
      while (__hip_atomic_load(&cnt[g * TSTEPS + t], __ATOMIC_RELAXED,
                               __HIP_MEMORY_SCOPE_AGENT) < 16u) {
        if (++guard > (1 << 20)) break;  // fail-safe: wrong answer instead of hang
      }
      asm volatile("" ::: "memory");  // pin h loads after poll
    }
    // LDS reuse safe: syncthreads above means all waves finished LDS reads.
  }
}

// ---------------- BatchNorm (training stats, biased var) + f16 cast ----------------
__global__ __launch_bounds__(256) void bn_kernel(const float* __restrict__ hf,
                                                 const float* __restrict__ gamma,
                                                 const float* __restrict__ beta,
                                                 f16* __restrict__ hbn) {
  int j = blockIdx.x * 256 + threadIdx.x;  // 1024 cols
  float s1 = 0.f, s2 = 0.f;
  for (int b = 0; b < BATCH; ++b) {
    float v = hf[(size_t)b * HIDDEN + j];
    s1 += v;
    s2 += v * v;
  }
  float mean = s1 * (1.f / BATCH);
  float var = s2 * (1.f / BATCH) - mean * mean;
  float sc = gamma[j] * rsqrtf(var + 1e-5f);
  float sh = beta[j] - mean * sc;
  for (int b = 0; b < BATCH; ++b)
    hbn[(size_t)b * HIDDEN + j] = (f16)(hf[(size_t)b * HIDDEN + j] * sc + sh);
}

// ---------------- launch ----------------
extern "C" void kernel_launch(void* const* d_in, const int* in_sizes, int n_in,
                              void* d_out, int out_size, void* d_ws, size_t ws_size,
                              hipStream_t stream) {
  (void)in_sizes; (void)n_in; (void)out_size;
  const float* x     = (const float*)d_in[0];
  const float* Wi    = (const float*)d_in[1];
  const float* bi    = (const float*)d_in[2];
  const float* Wh    = (const float*)d_in[3];
  const float* bh    = (const float*)d_in[4];
  const float* gamma = (const float*)d_in[5];
  const float* beta  = (const float*)d_in[6];
  const float* Wl    = (const float*)d_in[7];
  const float* bl    = (const float*)d_in[8];
  float* out = (float*)d_out;

  char* wsp = (char*)d_ws;
  size_t off = 0;
  auto alloc = [&](size_t bytes) -> void* {
    void* p = (void*)(wsp + off);
    off += (bytes + 255) & ~(size_t)255;
    return p;
  };
  f16*      Zb    = (f16*)alloc((size_t)TSTEPS * BATCH * HIDDEN * 2);  // 256 MB
  f16*      xT    = (f16*)alloc((size_t)TSTEPS * BATCH * NSER * 2);    // 128 MB
  f16*      WhLh  = (f16*)alloc((size_t)HIDDEN * HIDDEN * 2);
  f16*      WiT   = (f16*)alloc((size_t)NSER * HIDDEN * 2);
  f16*      Wlh   = (f16*)alloc((size_t)NSER * HIDDEN * 2);
  f16*      Weff  = (f16*)alloc((size_t)HIDDEN * NSER * 2);
  float*    beff  = (float*)alloc(HIDDEN * 4);
  f16*      hbuf0 = (f16*)alloc((size_t)BATCH * HIDDEN * 2);
  f16*      hbuf1 = (f16*)alloc((size_t)BATCH * HIDDEN * 2);
  float*    hfin  = (float*)alloc((size_t)BATCH * HIDDEN * 4);
  f16*      hbn   = (f16*)alloc((size_t)BATCH * HIDDEN * 2);
  unsigned* cnt   = (unsigned*)alloc(16 * TSTEPS * 4);
  if (off > ws_size) return;  // workspace too small; fail visibly

  hipMemsetAsync(cnt, 0, 16 * TSTEPS * 4, stream);
  hipMemsetAsync(hbuf0, 0, (size_t)BATCH * HIDDEN * 2, stream);  // h_0 = 0

  convert_whl_kernel<<<4096, 256, 0, stream>>>(Wh, WhLh);
  transpose_wi_kernel<<<dim3(16, 32), 256, 0, stream>>>(Wi, WiT);
  convert_wl_kernel<<<2048, 256, 0, stream>>>(Wl, Wlh);
  beff_kernel<<<1024, 256, 0, stream>>>(Wh, bi, bh, beff);
  // Weff[j][n] = sum_k WhL[j][k] * WiT[n][k] : M=1024, N=512, K=1024
  gemm_f16_kernel<true, false><<<dim3(4, 8), 256, 0, stream>>>(WhLh, WiT, nullptr, Weff,
                                                               1024, NSER, HIDDEN);
  transpose_x_kernel<<<dim3(16, 16, 256), 256, 0, stream>>>(x, xT);
  // Z[(t,b)][j] = sum_n xT[(t,b)][n] * Weff[j][n] + beff[j] : M=131072, N=1024, K=512
  gemm_f16_kernel<true, true><<<dim3(8, 1024), 256, 0, stream>>>(xT, Weff, beff, Zb,
                                                                 TSTEPS * BATCH, HIDDEN, NSER);
  rnn_kernel<<<256, 256, 0, stream>>>(Wh, Zb, hbuf0, hbuf1, hfin, cnt);
  bn_kernel<<<4, 256, 0, stream>>>(hfin, gamma, beta, hbn);
  // out[b][i] = sum_j hbn[b][j] * Wl[i][j] + bl[i] : M=256, N=512, K=1024
  gemm_f16_kernel<false, true><<<dim3(4, 2), 256, 0, stream>>>(hbn, Wlh, bl, out,
                                                               BATCH, NSER, HIDDEN);
}